// Round 7
// baseline (325.080 us; speedup 1.0000x reference)
//
#include <hip/hip_runtime.h>
#include <hip/hip_cooperative_groups.h>
#include <math.h>

namespace cg = cooperative_groups;

// Third-order scattering via double-Parseval:
//   out[b,i,j] = (1/MN^2) * sum_n xa_{b,i}[n] * d_{b,j}[n]
// xa_i = abs_eps(inv2(F_i * X)/MN), d_j = Re(inv2_un(F_j^2 * X)), X = fft2(x).
// X in NATURAL frequency layout; inverse FFTs are conjugate-DIF (natural ->
// bit-reversed spatial); both fields share the permutation, dots unaffected.
//
// ONE cooperative dispatch, grid 256 x 1024 (1 block/CU), phases:
//  A: blocks 0,1: X_b = fft2(x_b); block 2: zero out.        grid.sync()
//  B: blocks 0..129: 66 d-fields + 64 xa-fields.             grid.sync()
//  C: 256 blocks = (b,i) x 4 k-quarters: LDS-staged xa, float4 d loads,
//     register acc, shfl reduce, 33 atomicAdds/block (~4 per address).

#define PI_F 3.14159265358979323846f

__device__ __forceinline__ void make_tw(int lane, float* twr, float* twi) {
#pragma unroll
  for (int s = 0; s < 6; ++s) {
    int h = 32 >> s;
    float ang = -PI_F * (float)(lane & (h - 1)) / (float)h;
    float sv, cv;
    __sincosf(ang, &sv, &cv);
    twr[s] = cv; twi[s] = sv;
  }
  float ang = -PI_F * (float)lane / 64.0f;
  float sv, cv;
  __sincosf(ang, &sv, &cv);
  twr[6] = cv; twi[6] = sv;
}

// DIF radix-2: natural-order input (lane t holds x[t], x[t+64]); output slot s
// holds X[brev7(s)]. S=+1: forward (W^-); S=-1: inverse, unnormalized (W^+).
template <int S>
__device__ __forceinline__ void fft128_dif(float& ar, float& ai, float& br, float& bi,
                                           const float* twr, const float* twi, int lane) {
  float s6r = twr[6], s6i = (S > 0) ? twi[6] : -twi[6];
  float ur = ar + br, ui = ai + bi;
  float vr = ar - br, vi = ai - bi;
  ar = ur; ai = ui;
  br = vr * s6r - vi * s6i;
  bi = vr * s6i + vi * s6r;
#pragma unroll
  for (int s = 0; s < 6; ++s) {
    int h = 32 >> s;
    float wr = twr[s], wi = (S > 0) ? twi[s] : -twi[s];
    bool hi = (lane & h) != 0;
    float pr, pi2;
    pr = __shfl_xor(ar, h, 64); pi2 = __shfl_xor(ai, h, 64);
    if (!hi) { ar += pr; ai += pi2; }
    else { float dr = pr - ar, di = pi2 - ai; ar = dr * wr - di * wi; ai = dr * wi + di * wr; }
    pr = __shfl_xor(br, h, 64); pi2 = __shfl_xor(bi, h, 64);
    if (!hi) { br += pr; bi += pi2; }
    else { float dr = pr - br, di = pi2 - bi; br = dr * wr - di * wi; bi = dr * wi + di * wr; }
  }
}

// rows (row r=8w+t, slots c=lane/lane+64) -> cols (col c=8w+ci, slots r=lane/lane+64)
// via 64KB tile in two 64-row chunks; XOR swizzle (c ^ (r&15)) => conflict-free.
__device__ __forceinline__ void transpose_r2c(float (&dr)[16], float (&di)[16],
    float (&er)[8], float (&ei)[8], float (&fr)[8], float (&fi2)[8],
    float2 (*tile)[128], int lane, int w) {
#pragma unroll
  for (int ch = 0; ch < 2; ++ch) {
    if ((w >> 3) == ch) {
#pragma unroll
      for (int t = 0; t < 8; ++t) {
        int r = w * 8 + t;
        int rr = r & 63, sw = r & 15;
        tile[rr][lane ^ sw] = make_float2(dr[2 * t], di[2 * t]);
        tile[rr][(lane + 64) ^ sw] = make_float2(dr[2 * t + 1], di[2 * t + 1]);
      }
    }
    __syncthreads();
    {
      int sw = lane & 15;
#pragma unroll
      for (int ci = 0; ci < 8; ++ci) {
        int c = w * 8 + ci;
        float2 v = tile[lane][c ^ sw];
        if (ch == 0) { er[ci] = v.x; ei[ci] = v.y; }
        else { fr[ci] = v.x; fi2[ci] = v.y; }
      }
    }
    __syncthreads();
  }
}

__global__ __launch_bounds__(1024) void k_all(const float* __restrict__ x,
    const float* __restrict__ F, float2* __restrict__ X, float* __restrict__ dfld,
    float* __restrict__ xa, float* __restrict__ out) {
  cg::grid_group grid = cg::this_grid();
  __shared__ float2 tile[64][128];
  int tid = threadIdx.x, lane = tid & 63, w = tid >> 6;
  int blk = blockIdx.x;
  float twr[7], twi[7]; make_tw(lane, twr, twi);
  float dr[16], di[16];
  float er[8], ei[8], fr[8], fi2[8];

  // ---------------- Phase A ----------------
  if (blk < 2) {
    int b = blk;
    const float* xb = x + b * 16384;
#pragma unroll
    for (int t = 0; t < 8; ++t) {  // rows u = 8w+t: fwd v-FFT (real input)
      int r = w * 8 + t;
      float ar = xb[r * 128 + lane], ai2 = 0.f, br = xb[r * 128 + lane + 64], bi = 0.f;
      fft128_dif<1>(ar, ai2, br, bi, twr, twi, lane);
      dr[2 * t] = ar; di[2 * t] = ai2; dr[2 * t + 1] = br; di[2 * t + 1] = bi;
    }
    transpose_r2c(dr, di, er, ei, fr, fi2, tile, lane, w);
    int u0 = __brev((unsigned)lane) >> 25;  // brev7(lane); brev7(lane+64)=u0+1
#pragma unroll
    for (int ci = 0; ci < 8; ++ci) {  // cols: fwd u-FFT, brev scatter-store
      int c = w * 8 + ci;
      float ar = er[ci], ai2 = ei[ci], br = fr[ci], bi = fi2[ci];
      fft128_dif<1>(ar, ai2, br, bi, twr, twi, lane);
      int vn = __brev((unsigned)c) >> 25;
      X[b * 16384 + u0 * 128 + vn] = make_float2(ar, ai2);
      X[b * 16384 + (u0 + 1) * 128 + vn] = make_float2(br, bi);
    }
  } else if (blk == 2) {
    if (tid < 1344) out[tid] = 0.f;
    if (tid < 320) out[tid + 1024] = 0.f;
  }
  __threadfence();
  grid.sync();

  // ---------------- Phase B ----------------
  if (blk < 130) {
    bool isd = (blk < 66);
    int b, f;
    float* optr;
    if (isd) {
      b = blk / 33; f = blk - b * 33;
      optr = dfld + blk * 16384;
    } else {
      int q = blk - 66; b = q >> 5; f = q & 31;
      optr = xa + q * 16384;
    }
    const float* Fb = F + f * 16384;
    const float2* Xb = X + b * 16384;
    // P1: rows u (natural): Y = F (or F^2) * X, inverse v-FFT
#pragma unroll
    for (int t = 0; t < 8; ++t) {
      int r = w * 8 + t;
      float2 x0 = Xb[r * 128 + lane];
      float2 x1 = Xb[r * 128 + lane + 64];
      float f0 = Fb[r * 128 + lane], f1 = Fb[r * 128 + lane + 64];
      if (isd) { f0 *= f0; f1 *= f1; }
      float ar = x0.x * f0, ai2 = x0.y * f0, br = x1.x * f1, bi = x1.y * f1;
      fft128_dif<-1>(ar, ai2, br, bi, twr, twi, lane);
      dr[2 * t] = ar; di[2 * t] = ai2; dr[2 * t + 1] = br; di[2 * t + 1] = bi;
    }
    transpose_r2c(dr, di, er, ei, fr, fi2, tile, lane, w);
    // P2: per col: inverse u-FFT, store Re (d) or abs_eps (xa).
    const float sc = 1.0f / 16384.0f;
#pragma unroll
    for (int ci = 0; ci < 8; ++ci) {
      int c = w * 8 + ci;
      float ar = er[ci], ai2 = ei[ci], br = fr[ci], bi = fi2[ci];
      fft128_dif<-1>(ar, ai2, br, bi, twr, twi, lane);
      if (isd) {
        optr[c * 128 + lane] = ar;
        optr[c * 128 + lane + 64] = br;
      } else {
        float t0r = ar * sc, t0i = ai2 * sc, t1r = br * sc, t1i = bi * sc;
        optr[c * 128 + lane] = sqrtf(t0r * t0r + t0i * t0i + 1e-6f);
        optr[c * 128 + lane + 64] = sqrtf(t1r * t1r + t1i * t1i + 1e-6f);
      }
    }
  }
  __threadfence();
  grid.sync();

  // ---------------- Phase C ----------------
  {
    int q = blk & 3;          // k-quarter
    int im = blk >> 2;        // b*32+i
    int b = im >> 5, i = im & 31;
    int k0 = q * 4096;
    float* xs = (float*)tile;       // 4096 floats = 16 KB
    float* red = xs + 4096;         // 33 floats
    const float4* xr4 = (const float4*)(xa + im * 16384 + k0);
    const float* db = dfld + b * 33 * 16384 + k0;
    ((float4*)xs)[tid] = xr4[tid];
    if (tid < 33) red[tid] = 0.f;
    __syncthreads();
    float4 xv = ((const float4*)xs)[tid];
    // group 0: j = 0..15
    {
      float acc[16];
#pragma unroll
      for (int j = 0; j < 16; ++j) acc[j] = 0.f;
#pragma unroll
      for (int j = 0; j < 16; ++j) {
        float4 d4 = ((const float4*)(db + j * 16384))[tid];
        acc[j] += xv.x * d4.x + xv.y * d4.y + xv.z * d4.z + xv.w * d4.w;
      }
#pragma unroll
      for (int j = 0; j < 16; ++j) {
#pragma unroll
        for (int off = 32; off > 0; off >>= 1) acc[j] += __shfl_xor(acc[j], off, 64);
        if (lane == 0) atomicAdd(&red[j], acc[j]);
      }
    }
    // group 1: j = 16..32
    {
      float acc[17];
#pragma unroll
      for (int j = 0; j < 17; ++j) acc[j] = 0.f;
#pragma unroll
      for (int j = 0; j < 17; ++j) {
        float4 d4 = ((const float4*)(db + (16 + j) * 16384))[tid];
        acc[j] += xv.x * d4.x + xv.y * d4.y + xv.z * d4.z + xv.w * d4.w;
      }
#pragma unroll
      for (int j = 0; j < 17; ++j) {
#pragma unroll
        for (int off = 32; off > 0; off >>= 1) acc[j] += __shfl_xor(acc[j], off, 64);
        if (lane == 0) atomicAdd(&red[16 + j], acc[j]);
      }
    }
    __syncthreads();
    if (tid < 33) {
      int j = tid;
      int j1 = i >> 3, l1 = i & 7;
      const int pref[4] = {0, 264, 464, 600};
      int per = (4 - j1) * 8 + 1;
      int start = pref[j1] + l1 * per;
      int pos = -1;
      if (j == 32) pos = start + per - 1;
      else {
        int j2 = j >> 3;
        if (j2 >= j1) pos = start + (j2 - j1) * 8 + (j & 7);
      }
      if (pos >= 0)
        atomicAdd(out + b * 672 + pos, red[j] * (1.0f / 16384.0f) * (1.0f / 16384.0f));
    }
  }
}

extern "C" void kernel_launch(void* const* d_in, const int* in_sizes, int n_in,
                              void* d_out, int out_size, void* d_ws, size_t ws_size,
                              hipStream_t stream) {
  (void)in_sizes; (void)n_in; (void)out_size; (void)ws_size;
  const float* x = (const float*)d_in[0];   // (2,1,128,128)
  const float* F = (const float*)d_in[1];   // (1,33,128,128)
  float* out = (float*)d_out;               // (2,672)
  char* ws = (char*)d_ws;
  // ws: X @0 (262144 B) | dfld @262144 (4325376 B) | xa @4587520 (4194304 B)
  float2* X = (float2*)(ws + 0);
  float* dfld = (float*)(ws + 262144);
  float* xa = (float*)(ws + 4587520);

  void* args[] = {(void*)&x, (void*)&F, (void*)&X, (void*)&dfld, (void*)&xa, (void*)&out};
  hipLaunchCooperativeKernel((const void*)k_all, dim3(256), dim3(1024), args, 0, stream);
}

// Round 10
// 124.816 us; speedup vs baseline: 2.6045x; 2.6045x over previous
//
#include <hip/hip_runtime.h>
#include <math.h>

// Third-order scattering via double-Parseval:
//   out[b,i,j] = (1/MN^2) * sum_n xa_{b,i}[n] * d_{b,j}[n]
// xa_i = abs_eps(inv2(F_i * X)/MN), d_j = Re(inv2_un(F_j^2 * X)), X = fft2(x).
// X in NATURAL frequency layout; inverse FFTs are conjugate-DIF (same DIF
// dataflow as forward, conjugated twiddles): natural freq input ->
// bit-reversed spatial output. Both fields share the permutation, so the
// spatial dot products are unaffected.
//
// Hard-won constraints:
//  - R7: cooperative single-kernel fusion regressed 2.8x (grid.sync spin +
//    VGPR-52 spill). Do not fuse.
//  - R8/R9: the inverse FFT MUST be the conjugate-DIF (span-64 stage FIRST,
//    h=32..1, forward-butterfly form, conjugated twiddles). The mirrored
//    DIT-style inverse (h=1..32, span-64 last) expects bit-reversed input
//    and silently breaks with natural-layout X/F (identical absmax both
//    rounds). DPP primitives were NOT the R8 bug (unproven either way).
//
// 3 dispatches:
//  k_prep   : blocks 0,1: X_b = fft2(x_b); block 2: zero out.
//  k_fields : 130 fat blocks: 66 d-fields + 64 xa-fields.
//  k_dot    : 256 blocks, XCD-affine (b,q) groups, float4 loads, shfl reduce.

#define PI_F 3.14159265358979323846f

__device__ __forceinline__ void make_tw(int lane, float* twr, float* twi) {
#pragma unroll
  for (int s = 0; s < 6; ++s) {
    int h = 32 >> s;
    float ang = -PI_F * (float)(lane & (h - 1)) / (float)h;
    float sv, cv;
    __sincosf(ang, &sv, &cv);
    twr[s] = cv; twi[s] = sv;
  }
  float ang = -PI_F * (float)lane / 64.0f;
  float sv, cv;
  __sincosf(ang, &sv, &cv);
  twr[6] = cv; twi[6] = sv;
}

// DIF radix-2: natural-order input (lane t holds x[t], x[t+64]); output slot s
// holds X[brev7(s)]. S=+1: forward (W^-); S=-1: inverse, unnormalized (W^+),
// SAME dataflow with conjugated twiddles (conjugate-DIF). [R6/R7-proven body]
template <int S>
__device__ __forceinline__ void fft128_dif(float& ar, float& ai, float& br, float& bi,
                                           const float* twr, const float* twi, int lane) {
  float s6r = twr[6], s6i = (S > 0) ? twi[6] : -twi[6];
  float ur = ar + br, ui = ai + bi;
  float vr = ar - br, vi = ai - bi;
  ar = ur; ai = ui;
  br = vr * s6r - vi * s6i;
  bi = vr * s6i + vi * s6r;
#pragma unroll
  for (int s = 0; s < 6; ++s) {
    int h = 32 >> s;
    float wr = twr[s], wi = (S > 0) ? twi[s] : -twi[s];
    bool hi = (lane & h) != 0;
    float pr, pi2;
    pr = __shfl_xor(ar, h, 64); pi2 = __shfl_xor(ai, h, 64);
    if (!hi) { ar += pr; ai += pi2; }
    else { float dr = pr - ar, di = pi2 - ai; ar = dr * wr - di * wi; ai = dr * wi + di * wr; }
    pr = __shfl_xor(br, h, 64); pi2 = __shfl_xor(bi, h, 64);
    if (!hi) { br += pr; bi += pi2; }
    else { float dr = pr - br, di = pi2 - bi; br = dr * wr - di * wi; bi = dr * wi + di * wr; }
  }
}

// rows (row r=8w+t, slots c=lane/lane+64) -> cols (col c=8w+ci, slots r=lane/lane+64)
// via 64KB tile in two 64-row chunks; XOR swizzle (c ^ (r&15)) => conflict-free.
__device__ __forceinline__ void transpose_r2c(float (&dr)[16], float (&di)[16],
    float (&er)[8], float (&ei)[8], float (&fr)[8], float (&fi2)[8],
    float2 (*tile)[128], int lane, int w) {
#pragma unroll
  for (int ch = 0; ch < 2; ++ch) {
    if ((w >> 3) == ch) {
#pragma unroll
      for (int t = 0; t < 8; ++t) {
        int r = w * 8 + t;
        int rr = r & 63, sw = r & 15;
        tile[rr][lane ^ sw] = make_float2(dr[2 * t], di[2 * t]);
        tile[rr][(lane + 64) ^ sw] = make_float2(dr[2 * t + 1], di[2 * t + 1]);
      }
    }
    __syncthreads();
    {
      int sw = lane & 15;
#pragma unroll
      for (int ci = 0; ci < 8; ++ci) {
        int c = w * 8 + ci;
        float2 v = tile[lane][c ^ sw];
        if (ch == 0) { er[ci] = v.x; ei[ci] = v.y; }
        else { fr[ci] = v.x; fi2[ci] = v.y; }
      }
    }
    __syncthreads();
  }
}

// blocks 0,1: X[b] = fft2(x[b]), stored in NATURAL (u,v) frequency layout.
// block 2: zero out[1344].
__global__ __launch_bounds__(1024, 2) void k_prep(const float* __restrict__ x,
    float2* __restrict__ X, float* __restrict__ out) {
  __shared__ float2 tile[64][128];
  int tid = threadIdx.x;
  if (blockIdx.x == 2) {
    if (tid < 1344) out[tid] = 0.f;
    if (tid < 320) out[tid + 1024] = 0.f;
    return;
  }
  int b = blockIdx.x;
  int lane = tid & 63, w = tid >> 6;
  float twr[7], twi[7]; make_tw(lane, twr, twi);
  const float* xb = x + b * 16384;
  float dr[16], di[16];
  float er[8], ei[8], fr[8], fi2[8];
#pragma unroll
  for (int t = 0; t < 8; ++t) {  // rows u = 8w+t: fwd v-FFT (real input)
    int r = w * 8 + t;
    float ar = xb[r * 128 + lane], ai2 = 0.f, br = xb[r * 128 + lane + 64], bi = 0.f;
    fft128_dif<1>(ar, ai2, br, bi, twr, twi, lane);
    dr[2 * t] = ar; di[2 * t] = ai2; dr[2 * t + 1] = br; di[2 * t + 1] = bi;
  }
  transpose_r2c(dr, di, er, ei, fr, fi2, tile, lane, w);
  int u0 = __brev((unsigned)lane) >> 25;  // brev7(lane); brev7(lane+64)=u0+1
#pragma unroll
  for (int ci = 0; ci < 8; ++ci) {  // cols: fwd u-FFT, brev scatter-store
    int c = w * 8 + ci;
    float ar = er[ci], ai2 = ei[ci], br = fr[ci], bi = fi2[ci];
    fft128_dif<1>(ar, ai2, br, bi, twr, twi, lane);
    int vn = __brev((unsigned)c) >> 25;
    X[b * 16384 + u0 * 128 + vn] = make_float2(ar, ai2);
    X[b * 16384 + (u0 + 1) * 128 + vn] = make_float2(br, bi);
  }
}

// blocks 0..65:  (b,j): d  = Re(inv2_un(F_j^2 * X_b))          -> dfld[b*33+j]
// blocks 66..129:(b,i): xa = abs_eps(inv2_un(F_i * X_b)/MN)    -> xa[b*32+i]
// Fields stored in (sigma_sv col, sigma_su row) layout -- consistent for both.
__global__ __launch_bounds__(1024, 2) void k_fields(const float2* __restrict__ X,
    const float* __restrict__ F, float* __restrict__ dfld, float* __restrict__ xa) {
  __shared__ float2 tile[64][128];
  int tid = threadIdx.x, lane = tid & 63, w = tid >> 6;
  bool isd = (blockIdx.x < 66);
  int b, f;
  float* optr;
  if (isd) {
    b = blockIdx.x / 33; f = blockIdx.x - b * 33;
    optr = dfld + blockIdx.x * 16384;
  } else {
    int q = blockIdx.x - 66; b = q >> 5; f = q & 31;
    optr = xa + q * 16384;
  }
  const float* Fb = F + f * 16384;
  float twr[7], twi[7]; make_tw(lane, twr, twi);
  const float2* Xb = X + b * 16384;
  float dr[16], di[16];
  float er[8], ei[8], fr[8], fi2[8];

  // P1: rows u (natural): Y = F (or F^2) * X, inverse v-FFT (natural -> sigma_sv)
#pragma unroll
  for (int t = 0; t < 8; ++t) {
    int r = w * 8 + t;
    float2 x0 = Xb[r * 128 + lane];
    float2 x1 = Xb[r * 128 + lane + 64];
    float f0 = Fb[r * 128 + lane], f1 = Fb[r * 128 + lane + 64];
    if (isd) { f0 *= f0; f1 *= f1; }
    float ar = x0.x * f0, ai2 = x0.y * f0, br = x1.x * f1, bi = x1.y * f1;
    fft128_dif<-1>(ar, ai2, br, bi, twr, twi, lane);
    dr[2 * t] = ar; di[2 * t] = ai2; dr[2 * t + 1] = br; di[2 * t + 1] = bi;
  }
  transpose_r2c(dr, di, er, ei, fr, fi2, tile, lane, w);

  // P2: per col sigma_sv: inverse u-FFT (natural -> sigma_su), store Re / abs_eps.
  const float sc = 1.0f / 16384.0f;
#pragma unroll
  for (int ci = 0; ci < 8; ++ci) {
    int c = w * 8 + ci;
    float ar = er[ci], ai2 = ei[ci], br = fr[ci], bi = fi2[ci];
    fft128_dif<-1>(ar, ai2, br, bi, twr, twi, lane);
    if (isd) {
      optr[c * 128 + lane] = ar;
      optr[c * 128 + lane + 64] = br;
    } else {
      float t0r = ar * sc, t0i = ai2 * sc, t1r = br * sc, t1i = bi * sc;
      optr[c * 128 + lane] = sqrtf(t0r * t0r + t0i * t0i + 1e-6f);
      optr[c * 128 + lane + 64] = sqrtf(t1r * t1r + t1i * t1i + 1e-6f);
    }
  }
}

// 256 blocks: blockIdx = i*8 + g, g = (q<<1)|b  (8 XCD-affine groups x 32 i).
// Consecutive blockIdx round-robins XCDs, so the 32 blocks of one group (same
// b,q -> same 540KB dfld quarter) share one XCD's L2. 512 thr, float4 loads,
// shfl-xor reduce, 33 LDS-atomic + 33 global-atomic adds per block.
__global__ __launch_bounds__(512) void k_dot(const float* __restrict__ xa,
    const float* __restrict__ dfld, float* __restrict__ out) {
  __shared__ float4 xs[1024];  // 16 KB
  __shared__ float red[33];
  int tid = threadIdx.x, lane = tid & 63;
  int g = blockIdx.x & 7, i = blockIdx.x >> 3;
  int b = g & 1, q = g >> 1;
  int im = b * 32 + i, k0 = q * 4096;
  const float4* xr4 = (const float4*)(xa + im * 16384 + k0);
  xs[tid] = xr4[tid];
  xs[tid + 512] = xr4[tid + 512];
  if (tid < 33) red[tid] = 0.f;
  __syncthreads();
  float4 x0 = xs[tid], x1 = xs[tid + 512];
  const float* db = dfld + b * 33 * 16384 + k0;
  float acc[33];
#pragma unroll
  for (int j = 0; j < 33; ++j) {
    const float4* dj = (const float4*)(db + j * 16384);
    float4 d0 = dj[tid], d1 = dj[tid + 512];
    acc[j] = x0.x * d0.x + x0.y * d0.y + x0.z * d0.z + x0.w * d0.w
           + x1.x * d1.x + x1.y * d1.y + x1.z * d1.z + x1.w * d1.w;
  }
#pragma unroll
  for (int j = 0; j < 33; ++j) {
    float s = acc[j];
#pragma unroll
    for (int off = 32; off > 0; off >>= 1) s += __shfl_xor(s, off, 64);
    if (lane == 0) atomicAdd(&red[j], s);
  }
  __syncthreads();
  if (tid < 33) {
    int j = tid;
    int j1 = i >> 3, l1 = i & 7;
    const int pref[4] = {0, 264, 464, 600};
    int per = (4 - j1) * 8 + 1;
    int start = pref[j1] + l1 * per;
    int pos = -1;
    if (j == 32) pos = start + per - 1;
    else {
      int j2 = j >> 3;
      if (j2 >= j1) pos = start + (j2 - j1) * 8 + (j & 7);
    }
    if (pos >= 0)
      atomicAdd(out + b * 672 + pos, red[j] * (1.0f / 16384.0f) * (1.0f / 16384.0f));
  }
}

extern "C" void kernel_launch(void* const* d_in, const int* in_sizes, int n_in,
                              void* d_out, int out_size, void* d_ws, size_t ws_size,
                              hipStream_t stream) {
  (void)in_sizes; (void)n_in; (void)out_size; (void)ws_size;
  const float* x = (const float*)d_in[0];   // (2,1,128,128)
  const float* F = (const float*)d_in[1];   // (1,33,128,128)
  float* out = (float*)d_out;               // (2,672)
  char* ws = (char*)d_ws;
  // ws: X @0 (262144 B) | dfld @262144 (4325376 B) | xa @4587520 (4194304 B)
  float2* X = (float2*)(ws + 0);
  float* dfld = (float*)(ws + 262144);
  float* xa = (float*)(ws + 4587520);

  hipLaunchKernelGGL(k_prep, dim3(3), dim3(1024), 0, stream, x, X, out);
  hipLaunchKernelGGL(k_fields, dim3(130), dim3(1024), 0, stream, X, F, dfld, xa);
  hipLaunchKernelGGL(k_dot, dim3(256), dim3(512), 0, stream, xa, dfld, out);
}

// Round 11
// 114.508 us; speedup vs baseline: 2.8389x; 1.0900x over previous
//
#include <hip/hip_runtime.h>
#include <math.h>

// Third-order scattering via double-Parseval:
//   out[b,i,j] = (1/MN^2) * sum_n xa_{b,i}[n] * d_{b,j}[n]
// xa_i = abs_eps(inv2(F_i * X)/MN), d_j = Re(inv2_un(F_j^2 * X)), X = fft2(x).
// X in NATURAL frequency layout; inverse FFTs are conjugate-DIF (same DIF
// dataflow as forward, conjugated twiddles): natural freq input ->
// bit-reversed spatial output. Both fields share the permutation, so the
// spatial dot products are unaffected.
//
// Hard-won constraints:
//  - R7: cooperative single-kernel fusion regressed 2.8x (grid.sync spin +
//    VGPR-52 spill). Do not fuse.
//  - R8/R9: the inverse FFT MUST be the conjugate-DIF (span-64 stage FIRST,
//    h=32..1, forward-butterfly form, conjugated twiddles). A DIT-style
//    mirrored inverse expects bit-reversed input and silently breaks.
//  - R10: k_dot float4+XCD-affine restructure coincided with +9us total and
//    a 137us cold-dispatch stall; reverted to the R6 body (115.8us best).
//
// 3 dispatches:
//  k_prep   : blocks 0,1: X_b = fft2(x_b); block 2: zero out.
//  k_fields : 130 fat blocks: 66 d-fields + 64 xa-fields.
//  k_dot    : 256 blocks = (b,i) x 4 k-slices; register acc[33], shfl reduce.

#define PI_F 3.14159265358979323846f

__device__ __forceinline__ void make_tw(int lane, float* twr, float* twi) {
#pragma unroll
  for (int s = 0; s < 6; ++s) {
    int h = 32 >> s;
    float ang = -PI_F * (float)(lane & (h - 1)) / (float)h;
    float sv, cv;
    __sincosf(ang, &sv, &cv);
    twr[s] = cv; twi[s] = sv;
  }
  float ang = -PI_F * (float)lane / 64.0f;
  float sv, cv;
  __sincosf(ang, &sv, &cv);
  twr[6] = cv; twi[6] = sv;
}

// DIF radix-2: natural-order input (lane t holds x[t], x[t+64]); output slot s
// holds X[brev7(s)]. S=+1: forward (W^-); S=-1: inverse, unnormalized (W^+),
// SAME dataflow with conjugated twiddles (conjugate-DIF). [R6/R7/R10-proven]
template <int S>
__device__ __forceinline__ void fft128_dif(float& ar, float& ai, float& br, float& bi,
                                           const float* twr, const float* twi, int lane) {
  float s6r = twr[6], s6i = (S > 0) ? twi[6] : -twi[6];
  float ur = ar + br, ui = ai + bi;
  float vr = ar - br, vi = ai - bi;
  ar = ur; ai = ui;
  br = vr * s6r - vi * s6i;
  bi = vr * s6i + vi * s6r;
#pragma unroll
  for (int s = 0; s < 6; ++s) {
    int h = 32 >> s;
    float wr = twr[s], wi = (S > 0) ? twi[s] : -twi[s];
    bool hi = (lane & h) != 0;
    float pr, pi2;
    pr = __shfl_xor(ar, h, 64); pi2 = __shfl_xor(ai, h, 64);
    if (!hi) { ar += pr; ai += pi2; }
    else { float dr = pr - ar, di = pi2 - ai; ar = dr * wr - di * wi; ai = dr * wi + di * wr; }
    pr = __shfl_xor(br, h, 64); pi2 = __shfl_xor(bi, h, 64);
    if (!hi) { br += pr; bi += pi2; }
    else { float dr = pr - br, di = pi2 - bi; br = dr * wr - di * wi; bi = dr * wi + di * wr; }
  }
}

// rows (row r=8w+t, slots c=lane/lane+64) -> cols (col c=8w+ci, slots r=lane/lane+64)
// via 64KB tile in two 64-row chunks; XOR swizzle (c ^ (r&15)) => conflict-free.
__device__ __forceinline__ void transpose_r2c(float (&dr)[16], float (&di)[16],
    float (&er)[8], float (&ei)[8], float (&fr)[8], float (&fi2)[8],
    float2 (*tile)[128], int lane, int w) {
#pragma unroll
  for (int ch = 0; ch < 2; ++ch) {
    if ((w >> 3) == ch) {
#pragma unroll
      for (int t = 0; t < 8; ++t) {
        int r = w * 8 + t;
        int rr = r & 63, sw = r & 15;
        tile[rr][lane ^ sw] = make_float2(dr[2 * t], di[2 * t]);
        tile[rr][(lane + 64) ^ sw] = make_float2(dr[2 * t + 1], di[2 * t + 1]);
      }
    }
    __syncthreads();
    {
      int sw = lane & 15;
#pragma unroll
      for (int ci = 0; ci < 8; ++ci) {
        int c = w * 8 + ci;
        float2 v = tile[lane][c ^ sw];
        if (ch == 0) { er[ci] = v.x; ei[ci] = v.y; }
        else { fr[ci] = v.x; fi2[ci] = v.y; }
      }
    }
    __syncthreads();
  }
}

// blocks 0,1: X[b] = fft2(x[b]), stored in NATURAL (u,v) frequency layout.
// block 2: zero out[1344].
__global__ __launch_bounds__(1024, 2) void k_prep(const float* __restrict__ x,
    float2* __restrict__ X, float* __restrict__ out) {
  __shared__ float2 tile[64][128];
  int tid = threadIdx.x;
  if (blockIdx.x == 2) {
    if (tid < 1344) out[tid] = 0.f;
    if (tid < 320) out[tid + 1024] = 0.f;
    return;
  }
  int b = blockIdx.x;
  int lane = tid & 63, w = tid >> 6;
  float twr[7], twi[7]; make_tw(lane, twr, twi);
  const float* xb = x + b * 16384;
  float dr[16], di[16];
  float er[8], ei[8], fr[8], fi2[8];
#pragma unroll
  for (int t = 0; t < 8; ++t) {  // rows u = 8w+t: fwd v-FFT (real input)
    int r = w * 8 + t;
    float ar = xb[r * 128 + lane], ai2 = 0.f, br = xb[r * 128 + lane + 64], bi = 0.f;
    fft128_dif<1>(ar, ai2, br, bi, twr, twi, lane);
    dr[2 * t] = ar; di[2 * t] = ai2; dr[2 * t + 1] = br; di[2 * t + 1] = bi;
  }
  transpose_r2c(dr, di, er, ei, fr, fi2, tile, lane, w);
  int u0 = __brev((unsigned)lane) >> 25;  // brev7(lane); brev7(lane+64)=u0+1
#pragma unroll
  for (int ci = 0; ci < 8; ++ci) {  // cols: fwd u-FFT, brev scatter-store
    int c = w * 8 + ci;
    float ar = er[ci], ai2 = ei[ci], br = fr[ci], bi = fi2[ci];
    fft128_dif<1>(ar, ai2, br, bi, twr, twi, lane);
    int vn = __brev((unsigned)c) >> 25;
    X[b * 16384 + u0 * 128 + vn] = make_float2(ar, ai2);
    X[b * 16384 + (u0 + 1) * 128 + vn] = make_float2(br, bi);
  }
}

// blocks 0..65:  (b,j): d  = Re(inv2_un(F_j^2 * X_b))          -> dfld[b*33+j]
// blocks 66..129:(b,i): xa = abs_eps(inv2_un(F_i * X_b)/MN)    -> xa[b*32+i]
// Fields stored in (sigma_sv col, sigma_su row) layout -- consistent for both.
__global__ __launch_bounds__(1024, 2) void k_fields(const float2* __restrict__ X,
    const float* __restrict__ F, float* __restrict__ dfld, float* __restrict__ xa) {
  __shared__ float2 tile[64][128];
  int tid = threadIdx.x, lane = tid & 63, w = tid >> 6;
  bool isd = (blockIdx.x < 66);
  int b, f;
  float* optr;
  if (isd) {
    b = blockIdx.x / 33; f = blockIdx.x - b * 33;
    optr = dfld + blockIdx.x * 16384;
  } else {
    int q = blockIdx.x - 66; b = q >> 5; f = q & 31;
    optr = xa + q * 16384;
  }
  const float* Fb = F + f * 16384;
  float twr[7], twi[7]; make_tw(lane, twr, twi);
  const float2* Xb = X + b * 16384;
  float dr[16], di[16];
  float er[8], ei[8], fr[8], fi2[8];

  // P1: rows u (natural): Y = F (or F^2) * X, inverse v-FFT (natural -> sigma_sv)
#pragma unroll
  for (int t = 0; t < 8; ++t) {
    int r = w * 8 + t;
    float2 x0 = Xb[r * 128 + lane];
    float2 x1 = Xb[r * 128 + lane + 64];
    float f0 = Fb[r * 128 + lane], f1 = Fb[r * 128 + lane + 64];
    if (isd) { f0 *= f0; f1 *= f1; }
    float ar = x0.x * f0, ai2 = x0.y * f0, br = x1.x * f1, bi = x1.y * f1;
    fft128_dif<-1>(ar, ai2, br, bi, twr, twi, lane);
    dr[2 * t] = ar; di[2 * t] = ai2; dr[2 * t + 1] = br; di[2 * t + 1] = bi;
  }
  transpose_r2c(dr, di, er, ei, fr, fi2, tile, lane, w);

  // P2: per col sigma_sv: inverse u-FFT (natural -> sigma_su), store Re / abs_eps.
  const float sc = 1.0f / 16384.0f;
#pragma unroll
  for (int ci = 0; ci < 8; ++ci) {
    int c = w * 8 + ci;
    float ar = er[ci], ai2 = ei[ci], br = fr[ci], bi = fi2[ci];
    fft128_dif<-1>(ar, ai2, br, bi, twr, twi, lane);
    if (isd) {
      optr[c * 128 + lane] = ar;
      optr[c * 128 + lane + 64] = br;
    } else {
      float t0r = ar * sc, t0i = ai2 * sc, t1r = br * sc, t1i = bi * sc;
      optr[c * 128 + lane] = sqrtf(t0r * t0r + t0i * t0i + 1e-6f);
      optr[c * 128 + lane + 64] = sqrtf(t1r * t1r + t1i * t1i + 1e-6f);
    }
  }
}

// [R6-proven body] 256 blocks = (b,i)[64] x k-slice[4]; 512 threads; register
// acc[33]; wave shfl-reduce -> LDS[8][33] -> 33 atomicAdds per block.
__global__ __launch_bounds__(512) void k_dot(const float* __restrict__ xa,
    const float* __restrict__ dfld, float* __restrict__ out) {
  int im = blockIdx.x >> 2;        // 0..63  (b*32+i)
  int slice = blockIdx.x & 3;
  int b = im >> 5, i = im & 31;
  int t = threadIdx.x;             // 0..511
  const float* xr = xa + im * 16384 + slice * 4096;
  const float* db = dfld + b * 33 * 16384 + slice * 4096;
  float acc[33];
#pragma unroll
  for (int j = 0; j < 33; ++j) acc[j] = 0.f;
#pragma unroll
  for (int it = 0; it < 8; ++it) {
    int k = it * 512 + t;
    float xv = xr[k];
#pragma unroll
    for (int j = 0; j < 33; ++j) acc[j] += xv * db[j * 16384 + k];
  }
  // wave-level reduction per j
#pragma unroll
  for (int j = 0; j < 33; ++j) {
#pragma unroll
    for (int off = 32; off > 0; off >>= 1) acc[j] += __shfl_xor(acc[j], off, 64);
  }
  __shared__ float red[8][33];
  int w = t >> 6, lane = t & 63;
  if (lane == 0) {
#pragma unroll
    for (int j = 0; j < 33; ++j) red[w][j] = acc[j];
  }
  __syncthreads();
  if (t < 33) {
    float s = 0.f;
#pragma unroll
    for (int w2 = 0; w2 < 8; ++w2) s += red[w2][t];
    // decode output position for (i, j=t)
    int j = t;
    int j1 = i >> 3, l1 = i & 7;
    const int pref[4] = {0, 264, 464, 600};
    int per = (4 - j1) * 8 + 1;
    int start = pref[j1] + l1 * per;
    int pos = -1;
    if (j == 32) pos = start + per - 1;
    else {
      int j2 = j >> 3;
      if (j2 >= j1) pos = start + (j2 - j1) * 8 + (j & 7);
    }
    if (pos >= 0)
      atomicAdd(out + b * 672 + pos, s * (1.0f / 16384.0f) * (1.0f / 16384.0f));
  }
}

extern "C" void kernel_launch(void* const* d_in, const int* in_sizes, int n_in,
                              void* d_out, int out_size, void* d_ws, size_t ws_size,
                              hipStream_t stream) {
  (void)in_sizes; (void)n_in; (void)out_size; (void)ws_size;
  const float* x = (const float*)d_in[0];   // (2,1,128,128)
  const float* F = (const float*)d_in[1];   // (1,33,128,128)
  float* out = (float*)d_out;               // (2,672)
  char* ws = (char*)d_ws;
  // ws: X @0 (262144 B) | dfld @262144 (4325376 B) | xa @4587520 (4194304 B)
  float2* X = (float2*)(ws + 0);
  float* dfld = (float*)(ws + 262144);
  float* xa = (float*)(ws + 4587520);

  hipLaunchKernelGGL(k_prep, dim3(3), dim3(1024), 0, stream, x, X, out);
  hipLaunchKernelGGL(k_fields, dim3(130), dim3(1024), 0, stream, X, F, dfld, xa);
  hipLaunchKernelGGL(k_dot, dim3(256), dim3(512), 0, stream, xa, dfld, out);
}